// Round 1
// 110.235 us; speedup vs baseline: 1.0195x; 1.0195x over previous
//
#include <hip/hip_runtime.h>

// Problem: B=8, T_en=T_de=D=U=256.
// out = de + softmax_e( sum_u tanh(ae[b,e,u]+ad[b,t,u]) * nu[u] ) @ en
// tanh(x) = 1 - 2/(e^{2x}+1);  e^{2x} = Ea * sd with
//   Ea[b,e,u] = exp2(C*ae), sd[b,t,u] = exp2(C*ad), C = 2*log2(e)  (both
//   precomputed in the gemm epilogue -> attn hot loop has NO transcendentals
//   except 1 rcp per 4 u).
// Softmax identity: mu = SUM(nu) - 2*acc, acc = sum_u nu/(E+1); SUM(nu)
// drops out -> alpha = exp2((min_acc - acc)*C) / sum.
// 4-way rcp combine: sum nu_i/A_i = (n01*p23 + n23*p01) / (p01*p23).
// NOTE (R10 post-mortem): do NOT deepen the Ea ring past 4 — cur[8]/nxt[8]
// spilled to scratch (45MB WRITE_SIZE, 2x attn time). 4-deep is the sweet spot.
// R12: both kernels were L2-BW-bound on operand re-reads (w: 256MB, Ea: 268MB,
// en: 256MB ~ 23us of the 32us kernel budget). ROWS 4->8 and TT 2->4 halve
// all three terms; VALU work unchanged. Grid 512 = 2 blocks/CU, so
// __launch_bounds__ relaxed to (256,2) for register headroom (no spills!).
// Harness note: ~80us/iter is fixed overhead (256MB d_ws poison = 40us fill
// + restores); kernel-compressible budget is only ~32us.

#define C2LOG2E 2.8853900817779268f   // 2*log2(e)

// Force a wave-uniform pointer value -> compiler can use scalar (s_load) path.
__device__ __forceinline__ const float* uptr(const float* p) {
    unsigned long long v = (unsigned long long)p;
    unsigned lo = __builtin_amdgcn_readfirstlane((unsigned)v);
    unsigned hi = __builtin_amdgcn_readfirstlane((unsigned)(v >> 32));
    return (const float*)((((unsigned long long)hi) << 32) | lo);
}

// ---------------------------------------------------------------------------
// Projection GEMMs + exp2 epilogue. grid 512 x 256thr:
//   blk<256 : Ea packed  att_enT4[b][u>>2][e][u&3] = exp2(C * (en@w_en))
//   blk>=256: sd         att_de_exp[b][t][u]       = exp2(C * (de@w_de))
// Block = 8 rows x 256 cols. Wave wv = k-quarter [64wv,64wv+64) for ALL 8
// rows (A via uniform s_load ptrs, w as coalesced b128, 4-deep prefetch);
// partials reduced through LDS (32KB).
// ---------------------------------------------------------------------------
__global__ __launch_bounds__(256, 2) void gemm2(
    const float* __restrict__ en, const float* __restrict__ de,
    const float* __restrict__ w_en, const float* __restrict__ w_de,
    float* __restrict__ att_enT4, float* __restrict__ att_de_exp)
{
    __shared__ float part[4 * 8 * 256];   // 32KB [wave][row][col]; reused

    const int isDe = blockIdx.x >> 8;
    const int rb   = blockIdx.x & 255;
    const float* x = isDe ? de : en;
    const float* w = isDe ? w_de : w_en;

    const int tid  = threadIdx.x;
    const int lane = tid & 63;
    const int wv   = __builtin_amdgcn_readfirstlane(tid >> 6);
    const int r0   = rb * 8;
    const int c0   = lane << 2;
    const int k0   = wv << 6;

    const float* ar[8];
    #pragma unroll
    for (int r = 0; r < 8; ++r)
        ar[r] = uptr(x + (r0 + r) * 256 + k0);
    const float* wk = w + k0 * 256 + c0;

    float4 acc[8];
    #pragma unroll
    for (int r = 0; r < 8; ++r) acc[r] = float4{0.f, 0.f, 0.f, 0.f};

    float4 wb[4], wn[4];
    #pragma unroll
    for (int j = 0; j < 4; ++j)
        wb[j] = *(const float4*)(wk + j * 256);

    for (int kk = 0; kk < 64; kk += 4) {
        if (kk < 60) {
            #pragma unroll
            for (int j = 0; j < 4; ++j)
                wn[j] = *(const float4*)(wk + (kk + 4 + j) * 256);
        }
        #pragma unroll
        for (int j = 0; j < 4; ++j) {
            const int k = kk + j;
            #pragma unroll
            for (int r = 0; r < 8; ++r) {
                const float a = ar[r][k];                    // s_load
                acc[r].x = fmaf(a, wb[j].x, acc[r].x);
                acc[r].y = fmaf(a, wb[j].y, acc[r].y);
                acc[r].z = fmaf(a, wb[j].z, acc[r].z);
                acc[r].w = fmaf(a, wb[j].w, acc[r].w);
            }
        }
        #pragma unroll
        for (int j = 0; j < 4; ++j) wb[j] = wn[j];
    }

    // write partials [wave][row][col]
    #pragma unroll
    for (int r = 0; r < 8; ++r)
        *(float4*)&part[(wv * 8 + r) * 256 + c0] = acc[r];
    __syncthreads();

    // reduce 4 k-partials; thread t = column; apply scale + exp2
    const int t = tid;
    float s[8];
    #pragma unroll
    for (int j = 0; j < 8; ++j) {
        const float v = part[(0 * 8 + j) * 256 + t] + part[(1 * 8 + j) * 256 + t]
                      + part[(2 * 8 + j) * 256 + t] + part[(3 * 8 + j) * 256 + t];
        s[j] = __builtin_amdgcn_exp2f(v * C2LOG2E);
    }

    if (isDe) {
        const int rr0 = r0 & 2047;          // rows within (B*T_de)
        #pragma unroll
        for (int j = 0; j < 8; ++j)
            att_de_exp[(rr0 + j) * 256 + t] = s[j];
    } else {
        const int b  = rb >> 5;
        const int er = (rb & 31) * 8;
        __syncthreads();                    // all part reads done
        #pragma unroll
        for (int j = 0; j < 8; ++j)
            part[j * 256 + t] = s[j];       // xs2[e_local][u]
        __syncthreads();
        const int ug = t >> 2;
        const int sl = t & 3;
        #pragma unroll
        for (int h = 0; h < 2; ++h) {
            const float4 v = *(const float4*)&part[(h * 4 + sl) * 256 + (ug << 2)];
            *(float4*)(att_enT4 + b * 65536 + ug * 1024 + (er + h * 4 + sl) * 4) = v;
        }
    }
}

// ---------------------------------------------------------------------------
// Attention. grid 512 x 256thr, TT=4, b = blk&7 (XCD-affine).
// Stage 1: lane = e; b128 loads of 4 packed Ea values per e (4-deep ring,
//   cur/nxt at FUNCTION scope — deeper rings spill, see R10 note);
//   sd/nu via uniform s_loads; E=Ea*sd; 4-way rcp combine; NO exp2 in loop.
//   Each Ea load now amortized over 4 t-rows (was 2).
// Stage 2: wave wv does softmax for t=wv (min-trick) — all 4 waves active.
// Stage 3: thread=d, alphas as uniform b128 broadcasts, en coalesced dword,
//   8-deep; en[b] read once per block now covers 4 output rows.
// ---------------------------------------------------------------------------
__global__ __launch_bounds__(256, 2) void attn_kernel(
    const float* __restrict__ att_enT4,   // (B,64,T_en,4): Ea packed
    const float* __restrict__ att_de_exp, // (B,T_de,U): sd
    const float* __restrict__ en_seq,     // (B,T_en,D)
    const float* __restrict__ de_seq,     // (B,T_de,D)
    const float* __restrict__ nu,         // (U)
    float* __restrict__ out)              // (B,T_de,D)
{
    const int blk  = blockIdx.x;          // 0..511
    const int b    = blk & 7;
    const int t0   = (blk >> 3) << 2;
    const int tid  = threadIdx.x;
    const int lane = tid & 63;
    const int wv   = __builtin_amdgcn_readfirstlane(tid >> 6);

    __shared__ float s_mu[4][256];
    __shared__ float s_al[4][256];

    const float* aw  = att_enT4 + b * 65536 + (((wv << 6) + lane) << 2);
    const float* sd0 = uptr(att_de_exp + (b * 256 + t0 + 0) * 256);
    const float* sd1 = uptr(att_de_exp + (b * 256 + t0 + 1) * 256);
    const float* sd2 = uptr(att_de_exp + (b * 256 + t0 + 2) * 256);
    const float* sd3 = uptr(att_de_exp + (b * 256 + t0 + 3) * 256);
    const float* nuu = uptr(nu);

    // ---- Stage 1: acc[t] = sum_u nu[u] / (Ea*sd + 1) ----
    float acc0 = 0.f, acc1 = 0.f, acc2 = 0.f, acc3 = 0.f;
    float4 cur[4], nxt[4];
    #pragma unroll
    for (int j = 0; j < 4; ++j)
        cur[j] = *(const float4*)(aw + j * 1024);

    for (int ugb = 0; ugb < 64; ugb += 4) {
        if (ugb < 60) {
            #pragma unroll
            for (int j = 0; j < 4; ++j)
                nxt[j] = *(const float4*)(aw + (ugb + 4 + j) * 1024);
        }
        #pragma unroll
        for (int j = 0; j < 4; ++j) {
            const int ub = (ugb + j) << 2;
            const float n0 = nuu[ub + 0], n1 = nuu[ub + 1];
            const float n2 = nuu[ub + 2], n3 = nuu[ub + 3];
            const float4 Ea = cur[j];
            {   // t = t0
                const float A0 = fmaf(Ea.x, sd0[ub + 0], 1.f);
                const float A1 = fmaf(Ea.y, sd0[ub + 1], 1.f);
                const float A2 = fmaf(Ea.z, sd0[ub + 2], 1.f);
                const float A3 = fmaf(Ea.w, sd0[ub + 3], 1.f);
                const float p01 = A0 * A1, p23 = A2 * A3;
                const float n01 = fmaf(n0, A1, n1 * A0);
                const float n23 = fmaf(n2, A3, n3 * A2);
                const float num = fmaf(n01, p23, n23 * p01);
                acc0 = fmaf(num, __builtin_amdgcn_rcpf(p01 * p23), acc0);
            }
            {   // t = t0+1
                const float A0 = fmaf(Ea.x, sd1[ub + 0], 1.f);
                const float A1 = fmaf(Ea.y, sd1[ub + 1], 1.f);
                const float A2 = fmaf(Ea.z, sd1[ub + 2], 1.f);
                const float A3 = fmaf(Ea.w, sd1[ub + 3], 1.f);
                const float p01 = A0 * A1, p23 = A2 * A3;
                const float n01 = fmaf(n0, A1, n1 * A0);
                const float n23 = fmaf(n2, A3, n3 * A2);
                const float num = fmaf(n01, p23, n23 * p01);
                acc1 = fmaf(num, __builtin_amdgcn_rcpf(p01 * p23), acc1);
            }
            {   // t = t0+2
                const float A0 = fmaf(Ea.x, sd2[ub + 0], 1.f);
                const float A1 = fmaf(Ea.y, sd2[ub + 1], 1.f);
                const float A2 = fmaf(Ea.z, sd2[ub + 2], 1.f);
                const float A3 = fmaf(Ea.w, sd2[ub + 3], 1.f);
                const float p01 = A0 * A1, p23 = A2 * A3;
                const float n01 = fmaf(n0, A1, n1 * A0);
                const float n23 = fmaf(n2, A3, n3 * A2);
                const float num = fmaf(n01, p23, n23 * p01);
                acc2 = fmaf(num, __builtin_amdgcn_rcpf(p01 * p23), acc2);
            }
            {   // t = t0+3
                const float A0 = fmaf(Ea.x, sd3[ub + 0], 1.f);
                const float A1 = fmaf(Ea.y, sd3[ub + 1], 1.f);
                const float A2 = fmaf(Ea.z, sd3[ub + 2], 1.f);
                const float A3 = fmaf(Ea.w, sd3[ub + 3], 1.f);
                const float p01 = A0 * A1, p23 = A2 * A3;
                const float n01 = fmaf(n0, A1, n1 * A0);
                const float n23 = fmaf(n2, A3, n3 * A2);
                const float num = fmaf(n01, p23, n23 * p01);
                acc3 = fmaf(num, __builtin_amdgcn_rcpf(p01 * p23), acc3);
            }
        }
        #pragma unroll
        for (int j = 0; j < 4; ++j) cur[j] = nxt[j];
    }
    const int eidx = (wv << 6) + lane;
    s_mu[0][eidx] = acc0;
    s_mu[1][eidx] = acc1;
    s_mu[2][eidx] = acc2;
    s_mu[3][eidx] = acc3;
    __syncthreads();

    // ---- Stage 2: softmax for t = wv (logits = const - 2*acc) ----
    {
        const float4 a = *(const float4*)&s_mu[wv][lane << 2];
        float mn = fminf(fminf(a.x, a.y), fminf(a.z, a.w));
        #pragma unroll
        for (int off = 32; off > 0; off >>= 1)
            mn = fminf(mn, __shfl_xor(mn, off, 64));
        const float p0 = __builtin_amdgcn_exp2f((mn - a.x) * C2LOG2E);
        const float p1 = __builtin_amdgcn_exp2f((mn - a.y) * C2LOG2E);
        const float p2 = __builtin_amdgcn_exp2f((mn - a.z) * C2LOG2E);
        const float p3 = __builtin_amdgcn_exp2f((mn - a.w) * C2LOG2E);
        float ssum = (p0 + p1) + (p2 + p3);
        #pragma unroll
        for (int off = 32; off > 0; off >>= 1)
            ssum += __shfl_xor(ssum, off, 64);
        const float inv = __builtin_amdgcn_rcpf(ssum);
        float4 al; al.x = p0 * inv; al.y = p1 * inv;
        al.z = p2 * inv; al.w = p3 * inv;
        *(float4*)&s_al[wv][lane << 2] = al;
    }
    __syncthreads();

    // ---- Stage 3: out[t][d] = de[t][d] + sum_e alpha[t][e]*en[e][d] ----
    const float* en_b = en_seq + b * 65536 + tid;
    float o0 = 0.f, o1 = 0.f, o2 = 0.f, o3 = 0.f;
    for (int e0 = 0; e0 < 256; e0 += 8) {
        float v[8];
        #pragma unroll
        for (int j = 0; j < 8; ++j) v[j] = en_b[(e0 + j) << 8];
        #pragma unroll
        for (int q = 0; q < 2; ++q) {
            const int eb = e0 + q * 4;
            const float4 A0 = *(const float4*)&s_al[0][eb];  // uniform bcast
            const float4 A1 = *(const float4*)&s_al[1][eb];
            const float4 A2 = *(const float4*)&s_al[2][eb];
            const float4 A3 = *(const float4*)&s_al[3][eb];
            o0 = fmaf(A0.x, v[q*4+0], o0); o1 = fmaf(A1.x, v[q*4+0], o1);
            o2 = fmaf(A2.x, v[q*4+0], o2); o3 = fmaf(A3.x, v[q*4+0], o3);
            o0 = fmaf(A0.y, v[q*4+1], o0); o1 = fmaf(A1.y, v[q*4+1], o1);
            o2 = fmaf(A2.y, v[q*4+1], o2); o3 = fmaf(A3.y, v[q*4+1], o3);
            o0 = fmaf(A0.z, v[q*4+2], o0); o1 = fmaf(A1.z, v[q*4+2], o1);
            o2 = fmaf(A2.z, v[q*4+2], o2); o3 = fmaf(A3.z, v[q*4+2], o3);
            o0 = fmaf(A0.w, v[q*4+3], o0); o1 = fmaf(A1.w, v[q*4+3], o1);
            o2 = fmaf(A2.w, v[q*4+3], o2); o3 = fmaf(A3.w, v[q*4+3], o3);
        }
    }
    const int base = (b * 256 + t0) * 256 + tid;
    out[base +   0] = de_seq[base +   0] + o0;
    out[base + 256] = de_seq[base + 256] + o1;
    out[base + 512] = de_seq[base + 512] + o2;
    out[base + 768] = de_seq[base + 768] + o3;
}

extern "C" void kernel_launch(void* const* d_in, const int* in_sizes, int n_in,
                              void* d_out, int out_size, void* d_ws, size_t ws_size,
                              hipStream_t stream) {
    const float* en_seq = (const float*)d_in[0];
    const float* de_seq = (const float*)d_in[1];
    const float* w_en   = (const float*)d_in[2];
    const float* w_de   = (const float*)d_in[3];
    const float* nu     = (const float*)d_in[4];
    float* out = (float*)d_out;

    float* att_enT4   = (float*)d_ws;                // 2MB: Ea, packed
    float* att_de_exp = att_enT4 + 8 * 256 * 256;    // 2MB: sd

    gemm2<<<512, 256, 0, stream>>>(en_seq, de_seq, w_en, w_de,
                                   att_enT4, att_de_exp);
    attn_kernel<<<512, 256, 0, stream>>>(att_enT4, att_de_exp, en_seq,
                                         de_seq, nu, out);
}

// Round 2
// 100.465 us; speedup vs baseline: 1.1187x; 1.0972x over previous
//
#include <hip/hip_runtime.h>

// Problem: B=8, T_en=T_de=D=U=256.
// out = de + softmax_e( sum_u tanh(ae[b,e,u]+ad[b,t,u]) * nu[u] ) @ en
// tanh(x) = 1 - 2/(e^{2x}+1);  e^{2x} = Ea * sd with
//   Ea[b,e,u] = exp2(C*ae), sd[b,t,u] = exp2(C*ad), C = 2*log2(e)  (both
//   precomputed in the gemm epilogue -> attn hot loop has NO transcendentals
//   except 1 rcp per 4 u).
// Softmax identity: mu = SUM(nu) - 2*acc, acc = sum_u nu/(E+1); SUM(nu)
// drops out -> alpha = exp2((min_acc - acc)*C) / sum.
// 4-way rcp combine: sum nu_i/A_i = (n01*p23 + n23*p01) / (p01*p23).
// NOTE (R10 post-mortem): do NOT deepen the Ea ring past 4 — cur[8]/nxt[8]
// spilled to scratch (45MB WRITE_SIZE, 2x attn time). 4-deep is the sweet spot.
// R12: ROWS 4->8, TT 2->4 halved L2 re-read traffic (w/Ea/en); dur 112.4->110.2.
// R13 post-mortem of R12: attn showed 41us @ VALUBusy 36%, Occ 17% -> latency-
// stalled, not BW/VALU bound. Suspect: wave-uniform s_loads (sd/nu rows, A rows)
// — SMEM returns out-of-order on gfx9-lineage, forcing lgkmcnt(0) drains every
// j-step; SMEM can't pipeline with counted waits. Fix: keep uniform-broadcast
// but through LDS (same-addr ds_read_b128 = free broadcast, in-order, counted
// lgkmcnt). sd+nu -> 5KB LDS in attn; 8 A-rows -> 8KB LDS in gemm2.
// Harness note: ~80us/iter is fixed overhead (256MB d_ws poison = 40us fill
// + restores); kernel-compressible budget is only ~32us.

#define C2LOG2E 2.8853900817779268f   // 2*log2(e)

// ---------------------------------------------------------------------------
// Projection GEMMs + exp2 epilogue. grid 512 x 256thr:
//   blk<256 : Ea packed  att_enT4[b][u>>2][e][u&3] = exp2(C * (en@w_en))
//   blk>=256: sd         att_de_exp[b][t][u]       = exp2(C * (de@w_de))
// Block = 8 rows x 256 cols. Wave wv = k-quarter [64wv,64wv+64) for ALL 8
// rows. A rows staged in LDS (8KB, coalesced preload, uniform b128 broadcast
// reads in the loop); w as coalesced b128, 4-deep prefetch; partials reduced
// through LDS (32KB).
// ---------------------------------------------------------------------------
__global__ __launch_bounds__(256, 2) void gemm2(
    const float* __restrict__ en, const float* __restrict__ de,
    const float* __restrict__ w_en, const float* __restrict__ w_de,
    float* __restrict__ att_enT4, float* __restrict__ att_de_exp)
{
    __shared__ float part[4 * 8 * 256];   // 32KB [wave][row][col]; reused
    __shared__ float s_a[8 * 256];        // 8KB: the 8 A rows

    const int isDe = blockIdx.x >> 8;
    const int rb   = blockIdx.x & 255;
    const float* x = isDe ? de : en;
    const float* w = isDe ? w_de : w_en;

    const int tid  = threadIdx.x;
    const int lane = tid & 63;
    const int wv   = __builtin_amdgcn_readfirstlane(tid >> 6);
    const int r0   = rb * 8;
    const int c0   = lane << 2;
    const int k0   = wv << 6;

    const float* wk = w + k0 * 256 + c0;

    // stage the 8 contiguous A rows (2048 floats) into LDS, coalesced
    const float* xrow = x + r0 * 256;
    #pragma unroll
    for (int i = 0; i < 8; ++i)
        s_a[i * 256 + tid] = xrow[i * 256 + tid];

    float4 acc[8];
    #pragma unroll
    for (int r = 0; r < 8; ++r) acc[r] = float4{0.f, 0.f, 0.f, 0.f};

    float4 wb[4], wn[4];
    #pragma unroll
    for (int j = 0; j < 4; ++j)
        wb[j] = *(const float4*)(wk + j * 256);

    __syncthreads();

    for (int kk = 0; kk < 64; kk += 4) {
        // uniform broadcast reads of A (in-order DS, counted lgkmcnt)
        float4 av[8];
        #pragma unroll
        for (int r = 0; r < 8; ++r)
            av[r] = *(const float4*)&s_a[r * 256 + k0 + kk];

        if (kk < 60) {
            #pragma unroll
            for (int j = 0; j < 4; ++j)
                wn[j] = *(const float4*)(wk + (kk + 4 + j) * 256);
        }

#define FMA_ALL(COMP, WJ)                                        \
        _Pragma("unroll")                                        \
        for (int r = 0; r < 8; ++r) {                            \
            const float a = av[r].COMP;                          \
            acc[r].x = fmaf(a, WJ.x, acc[r].x);                  \
            acc[r].y = fmaf(a, WJ.y, acc[r].y);                  \
            acc[r].z = fmaf(a, WJ.z, acc[r].z);                  \
            acc[r].w = fmaf(a, WJ.w, acc[r].w);                  \
        }
        FMA_ALL(x, wb[0])
        FMA_ALL(y, wb[1])
        FMA_ALL(z, wb[2])
        FMA_ALL(w, wb[3])
#undef FMA_ALL

        #pragma unroll
        for (int j = 0; j < 4; ++j) wb[j] = wn[j];
    }

    // write partials [wave][row][col]
    #pragma unroll
    for (int r = 0; r < 8; ++r)
        *(float4*)&part[(wv * 8 + r) * 256 + c0] = acc[r];
    __syncthreads();

    // reduce 4 k-partials; thread t = column; apply scale + exp2
    const int t = tid;
    float s[8];
    #pragma unroll
    for (int j = 0; j < 8; ++j) {
        const float v = part[(0 * 8 + j) * 256 + t] + part[(1 * 8 + j) * 256 + t]
                      + part[(2 * 8 + j) * 256 + t] + part[(3 * 8 + j) * 256 + t];
        s[j] = __builtin_amdgcn_exp2f(v * C2LOG2E);
    }

    if (isDe) {
        const int rr0 = r0 & 2047;          // rows within (B*T_de)
        #pragma unroll
        for (int j = 0; j < 8; ++j)
            att_de_exp[(rr0 + j) * 256 + t] = s[j];
    } else {
        const int b  = rb >> 5;
        const int er = (rb & 31) * 8;
        __syncthreads();                    // all part reads done
        #pragma unroll
        for (int j = 0; j < 8; ++j)
            part[j * 256 + t] = s[j];       // xs2[e_local][u]
        __syncthreads();
        const int ug = t >> 2;
        const int sl = t & 3;
        #pragma unroll
        for (int h = 0; h < 2; ++h) {
            const float4 v = *(const float4*)&part[(h * 4 + sl) * 256 + (ug << 2)];
            *(float4*)(att_enT4 + b * 65536 + ug * 1024 + (er + h * 4 + sl) * 4) = v;
        }
    }
}

// ---------------------------------------------------------------------------
// Attention. grid 512 x 256thr, TT=4, b = blk&7 (XCD-affine).
// Stage 0: preload sd rows (4KB) + nu (1KB) into LDS — hot loop reads them as
//   uniform ds_read_b128 broadcasts (in-order, counted lgkmcnt; no SMEM drain).
// Stage 1: lane = e; b128 loads of 4 packed Ea values per e (4-deep ring,
//   cur/nxt at FUNCTION scope — deeper rings spill, see R10 note);
//   E=Ea*sd; 4-way rcp combine; NO exp2 in loop.
// Stage 2: wave wv does softmax for t=wv (min-trick) — all 4 waves active.
// Stage 3: thread=d, alphas as uniform b128 broadcasts, en coalesced dword,
//   8-deep; en[b] read once per block covers 4 output rows.
// ---------------------------------------------------------------------------
__global__ __launch_bounds__(256, 2) void attn_kernel(
    const float* __restrict__ att_enT4,   // (B,64,T_en,4): Ea packed
    const float* __restrict__ att_de_exp, // (B,T_de,U): sd
    const float* __restrict__ en_seq,     // (B,T_en,D)
    const float* __restrict__ de_seq,     // (B,T_de,D)
    const float* __restrict__ nu,         // (U)
    float* __restrict__ out)              // (B,T_de,D)
{
    const int blk  = blockIdx.x;          // 0..511
    const int b    = blk & 7;
    const int t0   = (blk >> 3) << 2;
    const int tid  = threadIdx.x;
    const int lane = tid & 63;
    const int wv   = __builtin_amdgcn_readfirstlane(tid >> 6);

    __shared__ float s_mu[4][256];
    __shared__ float s_al[4][256];
    __shared__ float s_sd[4][256];        // 4KB: the 4 sd rows
    __shared__ float s_nu[256];           // 1KB

    const float* aw = att_enT4 + b * 65536 + (((wv << 6) + lane) << 2);

    // ---- Stage 0: stage sd + nu into LDS (coalesced; rows contiguous) ----
    const float* sdb = att_de_exp + (b * 256 + t0) * 256;   // 1024 floats
    #pragma unroll
    for (int r = 0; r < 4; ++r)
        s_sd[r][tid] = sdb[r * 256 + tid];
    s_nu[tid] = nu[tid];

    // issue first Ea ring batch before the barrier (vmcnt-counted, overlaps)
    float4 cur[4], nxt[4];
    #pragma unroll
    for (int j = 0; j < 4; ++j)
        cur[j] = *(const float4*)(aw + j * 1024);

    __syncthreads();

    // ---- Stage 1: acc[t] = sum_u nu[u] / (Ea*sd + 1) ----
    float acc0 = 0.f, acc1 = 0.f, acc2 = 0.f, acc3 = 0.f;

    for (int ugb = 0; ugb < 64; ugb += 4) {
        if (ugb < 60) {
            #pragma unroll
            for (int j = 0; j < 4; ++j)
                nxt[j] = *(const float4*)(aw + (ugb + 4 + j) * 1024);
        }
        #pragma unroll
        for (int j = 0; j < 4; ++j) {
            const int ub = (ugb + j) << 2;
            // uniform LDS broadcasts (free, conflict-less, in-order)
            const float4 nv = *(const float4*)&s_nu[ub];
            const float4 s0 = *(const float4*)&s_sd[0][ub];
            const float4 s1 = *(const float4*)&s_sd[1][ub];
            const float4 s2 = *(const float4*)&s_sd[2][ub];
            const float4 s3 = *(const float4*)&s_sd[3][ub];
            const float4 Ea = cur[j];
            {   // t = t0
                const float A0 = fmaf(Ea.x, s0.x, 1.f);
                const float A1 = fmaf(Ea.y, s0.y, 1.f);
                const float A2 = fmaf(Ea.z, s0.z, 1.f);
                const float A3 = fmaf(Ea.w, s0.w, 1.f);
                const float p01 = A0 * A1, p23 = A2 * A3;
                const float n01 = fmaf(nv.x, A1, nv.y * A0);
                const float n23 = fmaf(nv.z, A3, nv.w * A2);
                const float num = fmaf(n01, p23, n23 * p01);
                acc0 = fmaf(num, __builtin_amdgcn_rcpf(p01 * p23), acc0);
            }
            {   // t = t0+1
                const float A0 = fmaf(Ea.x, s1.x, 1.f);
                const float A1 = fmaf(Ea.y, s1.y, 1.f);
                const float A2 = fmaf(Ea.z, s1.z, 1.f);
                const float A3 = fmaf(Ea.w, s1.w, 1.f);
                const float p01 = A0 * A1, p23 = A2 * A3;
                const float n01 = fmaf(nv.x, A1, nv.y * A0);
                const float n23 = fmaf(nv.z, A3, nv.w * A2);
                const float num = fmaf(n01, p23, n23 * p01);
                acc1 = fmaf(num, __builtin_amdgcn_rcpf(p01 * p23), acc1);
            }
            {   // t = t0+2
                const float A0 = fmaf(Ea.x, s2.x, 1.f);
                const float A1 = fmaf(Ea.y, s2.y, 1.f);
                const float A2 = fmaf(Ea.z, s2.z, 1.f);
                const float A3 = fmaf(Ea.w, s2.w, 1.f);
                const float p01 = A0 * A1, p23 = A2 * A3;
                const float n01 = fmaf(nv.x, A1, nv.y * A0);
                const float n23 = fmaf(nv.z, A3, nv.w * A2);
                const float num = fmaf(n01, p23, n23 * p01);
                acc2 = fmaf(num, __builtin_amdgcn_rcpf(p01 * p23), acc2);
            }
            {   // t = t0+3
                const float A0 = fmaf(Ea.x, s3.x, 1.f);
                const float A1 = fmaf(Ea.y, s3.y, 1.f);
                const float A2 = fmaf(Ea.z, s3.z, 1.f);
                const float A3 = fmaf(Ea.w, s3.w, 1.f);
                const float p01 = A0 * A1, p23 = A2 * A3;
                const float n01 = fmaf(nv.x, A1, nv.y * A0);
                const float n23 = fmaf(nv.z, A3, nv.w * A2);
                const float num = fmaf(n01, p23, n23 * p01);
                acc3 = fmaf(num, __builtin_amdgcn_rcpf(p01 * p23), acc3);
            }
        }
        #pragma unroll
        for (int j = 0; j < 4; ++j) cur[j] = nxt[j];
    }
    const int eidx = (wv << 6) + lane;
    s_mu[0][eidx] = acc0;
    s_mu[1][eidx] = acc1;
    s_mu[2][eidx] = acc2;
    s_mu[3][eidx] = acc3;
    __syncthreads();

    // ---- Stage 2: softmax for t = wv (logits = const - 2*acc) ----
    {
        const float4 a = *(const float4*)&s_mu[wv][lane << 2];
        float mn = fminf(fminf(a.x, a.y), fminf(a.z, a.w));
        #pragma unroll
        for (int off = 32; off > 0; off >>= 1)
            mn = fminf(mn, __shfl_xor(mn, off, 64));
        const float p0 = __builtin_amdgcn_exp2f((mn - a.x) * C2LOG2E);
        const float p1 = __builtin_amdgcn_exp2f((mn - a.y) * C2LOG2E);
        const float p2 = __builtin_amdgcn_exp2f((mn - a.z) * C2LOG2E);
        const float p3 = __builtin_amdgcn_exp2f((mn - a.w) * C2LOG2E);
        float ssum = (p0 + p1) + (p2 + p3);
        #pragma unroll
        for (int off = 32; off > 0; off >>= 1)
            ssum += __shfl_xor(ssum, off, 64);
        const float inv = __builtin_amdgcn_rcpf(ssum);
        float4 al; al.x = p0 * inv; al.y = p1 * inv;
        al.z = p2 * inv; al.w = p3 * inv;
        *(float4*)&s_al[wv][lane << 2] = al;
    }
    __syncthreads();

    // ---- Stage 3: out[t][d] = de[t][d] + sum_e alpha[t][e]*en[e][d] ----
    const float* en_b = en_seq + b * 65536 + tid;
    float o0 = 0.f, o1 = 0.f, o2 = 0.f, o3 = 0.f;
    for (int e0 = 0; e0 < 256; e0 += 8) {
        float v[8];
        #pragma unroll
        for (int j = 0; j < 8; ++j) v[j] = en_b[(e0 + j) << 8];
        #pragma unroll
        for (int q = 0; q < 2; ++q) {
            const int eb = e0 + q * 4;
            const float4 A0 = *(const float4*)&s_al[0][eb];  // uniform bcast
            const float4 A1 = *(const float4*)&s_al[1][eb];
            const float4 A2 = *(const float4*)&s_al[2][eb];
            const float4 A3 = *(const float4*)&s_al[3][eb];
            o0 = fmaf(A0.x, v[q*4+0], o0); o1 = fmaf(A1.x, v[q*4+0], o1);
            o2 = fmaf(A2.x, v[q*4+0], o2); o3 = fmaf(A3.x, v[q*4+0], o3);
            o0 = fmaf(A0.y, v[q*4+1], o0); o1 = fmaf(A1.y, v[q*4+1], o1);
            o2 = fmaf(A2.y, v[q*4+1], o2); o3 = fmaf(A3.y, v[q*4+1], o3);
            o0 = fmaf(A0.z, v[q*4+2], o0); o1 = fmaf(A1.z, v[q*4+2], o1);
            o2 = fmaf(A2.z, v[q*4+2], o2); o3 = fmaf(A3.z, v[q*4+2], o3);
            o0 = fmaf(A0.w, v[q*4+3], o0); o1 = fmaf(A1.w, v[q*4+3], o1);
            o2 = fmaf(A2.w, v[q*4+3], o2); o3 = fmaf(A3.w, v[q*4+3], o3);
        }
    }
    const int base = (b * 256 + t0) * 256 + tid;
    out[base +   0] = de_seq[base +   0] + o0;
    out[base + 256] = de_seq[base + 256] + o1;
    out[base + 512] = de_seq[base + 512] + o2;
    out[base + 768] = de_seq[base + 768] + o3;
}

extern "C" void kernel_launch(void* const* d_in, const int* in_sizes, int n_in,
                              void* d_out, int out_size, void* d_ws, size_t ws_size,
                              hipStream_t stream) {
    const float* en_seq = (const float*)d_in[0];
    const float* de_seq = (const float*)d_in[1];
    const float* w_en   = (const float*)d_in[2];
    const float* w_de   = (const float*)d_in[3];
    const float* nu     = (const float*)d_in[4];
    float* out = (float*)d_out;

    float* att_enT4   = (float*)d_ws;                // 2MB: Ea, packed
    float* att_de_exp = att_enT4 + 8 * 256 * 256;    // 2MB: sd

    gemm2<<<512, 256, 0, stream>>>(en_seq, de_seq, w_en, w_de,
                                   att_enT4, att_de_exp);
    attn_kernel<<<512, 256, 0, stream>>>(att_enT4, att_de_exp, en_seq,
                                         de_seq, nu, out);
}